// Round 1
// baseline (581.147 us; speedup 1.0000x reference)
//
#include <hip/hip_runtime.h>

#define N_NODES   4194304
#define LEVELS    10
#define COARSE    8192
#define NNZ_E     8388608
#define NCHUNK    16384   // N_NODES / 256

// ---------------- Kernel A: per-256-chunk moments M0 = sum z*(1-f), M1 = sum z*f
__global__ __launch_bounds__(256) void kA_moments(const float* __restrict__ z,
                                                  float2* __restrict__ M) {
    int lane = threadIdx.x & 63;
    int wave = threadIdx.x >> 6;
    int chunk = blockIdx.x * 4 + wave;          // one wave per 256-node chunk
    int base = chunk * 256 + lane * 4;
    float4 zv = *(const float4*)(z + base);
    float a0 = 0.f, a1 = 0.f;
    const float* zp = (const float*)&zv;
#pragma unroll
    for (int j = 0; j < 4; ++j) {
        float p = ((float)(base + j) + 0.5f) * (1.0f / 512.0f) - 0.5f;
        p = fminf(fmaxf(p, 0.0f), (float)(COARSE - 1));
        float f = p - floorf(p);                // i0 constant within chunk
        a0 += zp[j] * (1.0f - f);
        a1 += zp[j] * f;
    }
#pragma unroll
    for (int off = 32; off >= 1; off >>= 1) {
        a0 += __shfl_xor(a0, off, 64);
        a1 += __shfl_xor(a1, off, 64);
    }
    if (lane == 0) M[chunk] = make_float2(a0, a1);
}

// ---------------- Kernel B: block sums S[lvl][b][r] from moments (S must be zeroed)
__global__ __launch_bounds__(1024) void kB_ssum(const float2* __restrict__ M,
                                                const float* __restrict__ V,
                                                float* __restrict__ S) {
    int lvl = blockIdx.x;                 // one workgroup per level
    int t = threadIdx.x;                  // 1024 threads, 16 chunks each
    const float2* Vl = (const float2*)(V + lvl * COARSE * 2);
    float s0 = 0.f, s1 = 0.f;
    int c0 = t * 16;
#pragma unroll
    for (int cc = 0; cc < 16; ++cc) {
        int c = c0 + cc;
        float2 m = M[c];
        int k = (c > 0) ? ((c - 1) >> 1) : 0;
        int kp = min(k + 1, COARSE - 1);
        float2 vk = Vl[k], vkp = Vl[kp];
        s0 += vk.x * m.x + vkp.x * m.y;
        s1 += vk.y * m.x + vkp.y * m.y;
    }
    int gs = 1 << (9 - lvl);              // threads per block-group
    int gw = min(gs, 64);
    for (int sh = gw >> 1; sh >= 1; sh >>= 1) {
        s0 += __shfl_xor(s0, sh, 64);
        s1 += __shfl_xor(s1, sh, 64);
    }
    if ((t & (gw - 1)) == 0) {
        int b = t >> (9 - lvl);
        int soff = (2 << lvl) - 2;        // 2^(lvl+1) - 2
        unsafeAtomicAdd(&S[(soff + b) * 2 + 0], s0);
        unsafeAtomicAdd(&S[(soff + b) * 2 + 1], s1);
    }
}

// ---------------- Kernel C: per-chunk coefficients G0,G1 = sum_lvl,r u[k]*S[lvl][sib]
__global__ __launch_bounds__(256) void kC_g(const float* __restrict__ S,
                                            const float* __restrict__ U,
                                            float2* __restrict__ G) {
    int c = blockIdx.x * 256 + threadIdx.x;
    int k = (c > 0) ? ((c - 1) >> 1) : 0;
    int kp = min(k + 1, COARSE - 1);
    float g0 = 0.f, g1 = 0.f;
#pragma unroll
    for (int lvl = 0; lvl < LEVELS; ++lvl) {
        int sib = (c >> (13 - lvl)) ^ 1;
        int soff = (2 << lvl) - 2;
        float2 s = ((const float2*)S)[soff + sib];
        const float2* Ul = (const float2*)(U + lvl * COARSE * 2);
        float2 uk = Ul[k], ukp = Ul[kp];
        g0 += uk.x * s.x + uk.y * s.y;
        g1 += ukp.x * s.x + ukp.y * s.y;
    }
    G[c] = make_float2(g0, g1);
}

// ---------------- Kernel W: w = diag*z + (1-f)*G0 + f*G1 ; also zero-init y
__global__ __launch_bounds__(256) void kW(const float* __restrict__ diag,
                                          const float* __restrict__ z,
                                          const float2* __restrict__ G,
                                          float* __restrict__ w,
                                          float* __restrict__ y) {
    int tid = blockIdx.x * 256 + threadIdx.x;
    int base = tid * 4;
    float2 g = G[base >> 8];              // wave-uniform (256 nodes per wave)
    float4 d4 = *(const float4*)(diag + base);
    float4 z4 = *(const float4*)(z + base);
    float4 w4;
    const float* dp = (const float*)&d4;
    const float* zp = (const float*)&z4;
    float* wp = (float*)&w4;
#pragma unroll
    for (int j = 0; j < 4; ++j) {
        float p = ((float)(base + j) + 0.5f) * (1.0f / 512.0f) - 0.5f;
        p = fminf(fmaxf(p, 0.0f), (float)(COARSE - 1));
        float f = p - floorf(p);
        wp[j] = dp[j] * zp[j] + (g.x + f * (g.y - g.x));
    }
    *(float4*)(w + base) = w4;
    *(float4*)(y + base) = make_float4(0.f, 0.f, 0.f, 0.f);
}

// ---------------- Kernel S: COO scatter y[row] += val * w[col]
__global__ __launch_bounds__(256) void kScatter(const int* __restrict__ rows,
                                                const int* __restrict__ cols,
                                                const float* __restrict__ vals,
                                                const float* __restrict__ w,
                                                float* __restrict__ y) {
    int tid = blockIdx.x * 256 + threadIdx.x;
    int e = tid * 4;
    int4 r4 = *(const int4*)(rows + e);
    int4 c4 = *(const int4*)(cols + e);
    float4 v4 = *(const float4*)(vals + e);
    float w0 = w[c4.x], w1 = w[c4.y], w2 = w[c4.z], w3 = w[c4.w];
    unsafeAtomicAdd(&y[r4.x], v4.x * w0);
    unsafeAtomicAdd(&y[r4.y], v4.y * w1);
    unsafeAtomicAdd(&y[r4.z], v4.z * w2);
    unsafeAtomicAdd(&y[r4.w], v4.w * w3);
}

// ---------------- Kernel L: loss = mean((y - z)^2)  (d_out must be zeroed)
__global__ __launch_bounds__(256) void kLoss(const float* __restrict__ y,
                                             const float* __restrict__ z,
                                             float* __restrict__ out) {
    __shared__ float red[4];
    int t = threadIdx.x;
    float acc = 0.f;
    int base = blockIdx.x * 4096 + t * 4;     // 1024 blocks x 4096 nodes
#pragma unroll
    for (int rep = 0; rep < 4; ++rep) {
        int i = base + rep * 1024;
        float4 yv = *(const float4*)(y + i);
        float4 zv = *(const float4*)(z + i);
        float dx = yv.x - zv.x, dy = yv.y - zv.y;
        float dzz = yv.z - zv.z, dw = yv.w - zv.w;
        acc += dx * dx + dy * dy + dzz * dzz + dw * dw;
    }
#pragma unroll
    for (int off = 32; off >= 1; off >>= 1) acc += __shfl_xor(acc, off, 64);
    int lane = t & 63, wave = t >> 6;
    if (lane == 0) red[wave] = acc;
    __syncthreads();
    if (t == 0) {
        float s = red[0] + red[1] + red[2] + red[3];
        unsafeAtomicAdd(out, s * (1.0f / (float)N_NODES));
    }
}

extern "C" void kernel_launch(void* const* d_in, const int* in_sizes, int n_in,
                              void* d_out, int out_size, void* d_ws, size_t ws_size,
                              hipStream_t stream) {
    const float* diag  = (const float*)d_in[0];
    const float* U     = (const float*)d_in[1];
    const float* V     = (const float*)d_in[2];
    const float* Avals = (const float*)d_in[3];
    const float* z     = (const float*)d_in[4];
    const int*   Aidx  = (const int*)d_in[5];

    char* ws = (char*)d_ws;
    float*  w  = (float*)(ws);                                   // 16 MiB
    float*  y  = (float*)(ws + 16777216);                        // 16 MiB
    float2* M  = (float2*)(ws + 2 * 16777216);                   // 128 KiB
    float*  S  = (float*)(ws + 2 * 16777216 + 131072);           // 16 KiB
    float2* G  = (float2*)(ws + 2 * 16777216 + 131072 + 16384);  // 128 KiB

    hipMemsetAsync(S, 0, 2046 * 2 * sizeof(float), stream);
    hipMemsetAsync(d_out, 0, sizeof(float), stream);

    kA_moments<<<NCHUNK / 4, 256, 0, stream>>>(z, M);
    kB_ssum<<<LEVELS, 1024, 0, stream>>>(M, V, S);
    kC_g<<<NCHUNK / 256, 256, 0, stream>>>(S, U, G);
    kW<<<N_NODES / 1024, 256, 0, stream>>>(diag, z, G, w, y);
    kScatter<<<NNZ_E / 1024, 256, 0, stream>>>(Aidx, Aidx + NNZ_E, Avals, w, y);
    kLoss<<<1024, 256, 0, stream>>>(y, z, (float*)d_out);
}

// Round 2
// 438.872 us; speedup vs baseline: 1.3242x; 1.3242x over previous
//
#include <hip/hip_runtime.h>

#define N_NODES   4194304
#define LEVELS    10
#define COARSE    8192
#define NNZ_E     8388608
#define NCHUNK    16384   // N_NODES / 256
#define NBUCK     512     // buckets for row binning
#define BROWS     8192    // rows per bucket (N_NODES / NBUCK), 32 KiB LDS
#define HBLOCKS   1024    // blocks in hist/scatter pass (8192 edges each)

// ---------------- Kernel A: per-256-chunk moments M0 = sum z*(1-f), M1 = sum z*f
__global__ __launch_bounds__(256) void kA_moments(const float* __restrict__ z,
                                                  float2* __restrict__ M) {
    int lane = threadIdx.x & 63;
    int wave = threadIdx.x >> 6;
    int chunk = blockIdx.x * 4 + wave;
    int base = chunk * 256 + lane * 4;
    float4 zv = *(const float4*)(z + base);
    float a0 = 0.f, a1 = 0.f;
    const float* zp = (const float*)&zv;
#pragma unroll
    for (int j = 0; j < 4; ++j) {
        float p = ((float)(base + j) + 0.5f) * (1.0f / 512.0f) - 0.5f;
        p = fminf(fmaxf(p, 0.0f), (float)(COARSE - 1));
        float f = p - floorf(p);
        a0 += zp[j] * (1.0f - f);
        a1 += zp[j] * f;
    }
#pragma unroll
    for (int off = 32; off >= 1; off >>= 1) {
        a0 += __shfl_xor(a0, off, 64);
        a1 += __shfl_xor(a1, off, 64);
    }
    if (lane == 0) M[chunk] = make_float2(a0, a1);
}

// ---------------- Kernel B: block sums S[lvl][b][r] from moments (S zeroed by memset)
__global__ __launch_bounds__(1024) void kB_ssum(const float2* __restrict__ M,
                                                const float* __restrict__ V,
                                                float* __restrict__ S) {
    int lvl = blockIdx.x;
    int t = threadIdx.x;
    const float2* Vl = (const float2*)(V + lvl * COARSE * 2);
    float s0 = 0.f, s1 = 0.f;
    int c0 = t * 16;
#pragma unroll
    for (int cc = 0; cc < 16; ++cc) {
        int c = c0 + cc;
        float2 m = M[c];
        int k = (c > 0) ? ((c - 1) >> 1) : 0;
        int kp = min(k + 1, COARSE - 1);
        float2 vk = Vl[k], vkp = Vl[kp];
        s0 += vk.x * m.x + vkp.x * m.y;
        s1 += vk.y * m.x + vkp.y * m.y;
    }
    int gs = 1 << (9 - lvl);
    int gw = min(gs, 64);
    for (int sh = gw >> 1; sh >= 1; sh >>= 1) {
        s0 += __shfl_xor(s0, sh, 64);
        s1 += __shfl_xor(s1, sh, 64);
    }
    if ((t & (gw - 1)) == 0) {
        int b = t >> (9 - lvl);
        int soff = (2 << lvl) - 2;
        unsafeAtomicAdd(&S[(soff + b) * 2 + 0], s0);
        unsafeAtomicAdd(&S[(soff + b) * 2 + 1], s1);
    }
}

// ---------------- Kernel C: per-chunk coefficients G0,G1
__global__ __launch_bounds__(256) void kC_g(const float* __restrict__ S,
                                            const float* __restrict__ U,
                                            float2* __restrict__ G) {
    int c = blockIdx.x * 256 + threadIdx.x;
    int k = (c > 0) ? ((c - 1) >> 1) : 0;
    int kp = min(k + 1, COARSE - 1);
    float g0 = 0.f, g1 = 0.f;
#pragma unroll
    for (int lvl = 0; lvl < LEVELS; ++lvl) {
        int sib = (c >> (13 - lvl)) ^ 1;
        int soff = (2 << lvl) - 2;
        float2 s = ((const float2*)S)[soff + sib];
        const float2* Ul = (const float2*)(U + lvl * COARSE * 2);
        float2 uk = Ul[k], ukp = Ul[kp];
        g0 += uk.x * s.x + uk.y * s.y;
        g1 += ukp.x * s.x + ukp.y * s.y;
    }
    G[c] = make_float2(g0, g1);
}

// ---------------- Kernel W: w = diag*z + (1-f)*G0 + f*G1
__global__ __launch_bounds__(256) void kW(const float* __restrict__ diag,
                                          const float* __restrict__ z,
                                          const float2* __restrict__ G,
                                          float* __restrict__ w) {
    int tid = blockIdx.x * 256 + threadIdx.x;
    int base = tid * 4;
    float2 g = G[base >> 8];
    float4 d4 = *(const float4*)(diag + base);
    float4 z4 = *(const float4*)(z + base);
    float4 w4;
    const float* dp = (const float*)&d4;
    const float* zp = (const float*)&z4;
    float* wp = (float*)&w4;
#pragma unroll
    for (int j = 0; j < 4; ++j) {
        float p = ((float)(base + j) + 0.5f) * (1.0f / 512.0f) - 0.5f;
        p = fminf(fmaxf(p, 0.0f), (float)(COARSE - 1));
        float f = p - floorf(p);
        wp[j] = dp[j] * zp[j] + (g.x + f * (g.y - g.x));
    }
    *(float4*)(w + base) = w4;
}

// ---------------- Kernel H: per-block bucket histogram (counting sort pass 1)
__global__ __launch_bounds__(256) void kHist(const int* __restrict__ rows,
                                             unsigned int* __restrict__ blockOff) {
    __shared__ unsigned int h[NBUCK];
    int blk = blockIdx.x, t = threadIdx.x;
    for (int i = t; i < NBUCK; i += 256) h[i] = 0u;
    __syncthreads();
    int base = blk * 8192;
#pragma unroll
    for (int it = 0; it < 8; ++it) {
        int e = base + it * 1024 + t * 4;
        int4 r = *(const int4*)(rows + e);
        atomicAdd(&h[r.x >> 13], 1u);
        atomicAdd(&h[r.y >> 13], 1u);
        atomicAdd(&h[r.z >> 13], 1u);
        atomicAdd(&h[r.w >> 13], 1u);
    }
    __syncthreads();
    for (int i = t; i < NBUCK; i += 256) blockOff[i * HBLOCKS + blk] = h[i];
}

// ---------------- Scan 1: per-bucket exclusive scan over the 1024 block counts
__global__ __launch_bounds__(256) void kScan1(unsigned int* __restrict__ blockOff,
                                              unsigned int* __restrict__ total) {
    int b = blockIdx.x, t = threadIdx.x;
    unsigned int* p = blockOff + b * HBLOCKS;
    uint4 v = *(uint4*)(p + t * 4);
    unsigned int s = v.x + v.y + v.z + v.w;
    unsigned int incl = s;
#pragma unroll
    for (int off = 1; off < 64; off <<= 1) {
        unsigned int n = __shfl_up(incl, off, 64);
        if ((t & 63) >= off) incl += n;
    }
    __shared__ unsigned int wsum[4], wbase[4];
    if ((t & 63) == 63) wsum[t >> 6] = incl;
    __syncthreads();
    if (t == 0) {
        unsigned int acc = 0;
        for (int i = 0; i < 4; ++i) { wbase[i] = acc; acc += wsum[i]; }
        total[b] = acc;
    }
    __syncthreads();
    unsigned int excl = wbase[t >> 6] + incl - s;
    uint4 e;
    e.x = excl; e.y = excl + v.x; e.z = e.y + v.y; e.w = e.z + v.z;
    *(uint4*)(p + t * 4) = e;
}

// ---------------- Scan 2: exclusive scan of bucket totals -> bucket bases
__global__ __launch_bounds__(512) void kScan2(const unsigned int* __restrict__ total,
                                              unsigned int* __restrict__ bbase) {
    int t = threadIdx.x;
    unsigned int s = total[t];
    unsigned int incl = s;
#pragma unroll
    for (int off = 1; off < 64; off <<= 1) {
        unsigned int n = __shfl_up(incl, off, 64);
        if ((t & 63) >= off) incl += n;
    }
    __shared__ unsigned int wsum[8], wbase[8];
    if ((t & 63) == 63) wsum[t >> 6] = incl;
    __syncthreads();
    if (t == 0) {
        unsigned int acc = 0;
        for (int i = 0; i < 8; ++i) { wbase[i] = acc; acc += wsum[i]; }
    }
    __syncthreads();
    bbase[t] = wbase[t >> 6] + incl - s;
}

// ---------------- Kernel S: bin edges; packed entry = (row&8191, val*w[col])
__global__ __launch_bounds__(256) void kBinScatter(const int* __restrict__ rows,
                                                   const int* __restrict__ cols,
                                                   const float* __restrict__ vals,
                                                   const float* __restrict__ w,
                                                   const unsigned int* __restrict__ blockOff,
                                                   const unsigned int* __restrict__ bbase,
                                                   uint2* __restrict__ packed) {
    __shared__ unsigned int ctr[NBUCK];
    int blk = blockIdx.x, t = threadIdx.x;
    for (int i = t; i < NBUCK; i += 256) ctr[i] = bbase[i] + blockOff[i * HBLOCKS + blk];
    __syncthreads();
    int base = blk * 8192;
#pragma unroll
    for (int it = 0; it < 8; ++it) {
        int e = base + it * 1024 + t * 4;
        int4 r = *(const int4*)(rows + e);
        int4 c = *(const int4*)(cols + e);
        float4 v = *(const float4*)(vals + e);
        float w0 = w[c.x], w1 = w[c.y], w2 = w[c.z], w3 = w[c.w];
        unsigned int p0 = atomicAdd(&ctr[r.x >> 13], 1u);
        packed[p0] = make_uint2((unsigned)(r.x & 8191), __float_as_uint(v.x * w0));
        unsigned int p1 = atomicAdd(&ctr[r.y >> 13], 1u);
        packed[p1] = make_uint2((unsigned)(r.y & 8191), __float_as_uint(v.y * w1));
        unsigned int p2 = atomicAdd(&ctr[r.z >> 13], 1u);
        packed[p2] = make_uint2((unsigned)(r.z & 8191), __float_as_uint(v.z * w2));
        unsigned int p3 = atomicAdd(&ctr[r.w >> 13], 1u);
        packed[p3] = make_uint2((unsigned)(r.w & 8191), __float_as_uint(v.w * w3));
    }
}

// ---------------- Kernel Acc: per-bucket LDS accumulation + fused loss
__global__ __launch_bounds__(512) void kBucketAccum(const uint2* __restrict__ packed,
                                                    const unsigned int* __restrict__ bbase,
                                                    const unsigned int* __restrict__ total,
                                                    const float* __restrict__ z,
                                                    float* __restrict__ out) {
    __shared__ float acc[BROWS];
    int b = blockIdx.x, t = threadIdx.x;
    for (int i = t; i < BROWS / 4; i += 512) ((float4*)acc)[i] = make_float4(0.f, 0.f, 0.f, 0.f);
    __syncthreads();
    unsigned int s0 = bbase[b], n = total[b];
    for (unsigned int i = t; i < n; i += 512) {
        uint2 e = packed[s0 + i];
        atomicAdd(&acc[e.x], __uint_as_float(e.y));
    }
    __syncthreads();
    float part = 0.f;
    int gbase = b * BROWS;
    for (int i = t; i < BROWS; i += 512) {
        float d = acc[i] - z[gbase + i];
        part += d * d;
    }
#pragma unroll
    for (int off = 32; off >= 1; off >>= 1) part += __shfl_xor(part, off, 64);
    __shared__ float red[8];
    if ((t & 63) == 0) red[t >> 6] = part;
    __syncthreads();
    if (t == 0) {
        float s = 0.f;
        for (int i = 0; i < 8; ++i) s += red[i];
        unsafeAtomicAdd(out, s * (1.0f / (float)N_NODES));
    }
}

extern "C" void kernel_launch(void* const* d_in, const int* in_sizes, int n_in,
                              void* d_out, int out_size, void* d_ws, size_t ws_size,
                              hipStream_t stream) {
    const float* diag  = (const float*)d_in[0];
    const float* U     = (const float*)d_in[1];
    const float* V     = (const float*)d_in[2];
    const float* Avals = (const float*)d_in[3];
    const float* z     = (const float*)d_in[4];
    const int*   Aidx  = (const int*)d_in[5];
    const int* rows = Aidx;
    const int* cols = Aidx + NNZ_E;

    char* ws = (char*)d_ws;
    size_t off = 0;
    float*  w        = (float*)(ws + off);  off += (size_t)N_NODES * 4;          // 16 MiB
    uint2*  packed   = (uint2*)(ws + off);  off += (size_t)NNZ_E * 8;            // 64 MiB
    unsigned int* blockOff = (unsigned int*)(ws + off); off += (size_t)NBUCK * HBLOCKS * 4; // 2 MiB
    unsigned int* total    = (unsigned int*)(ws + off); off += NBUCK * 4;
    unsigned int* bbase    = (unsigned int*)(ws + off); off += NBUCK * 4;
    float2* M  = (float2*)(ws + off); off += NCHUNK * 8;                         // 128 KiB
    float*  S  = (float*)(ws + off);  off += 2046 * 2 * 4;                       // 16 KiB
    float2* G  = (float2*)(ws + off); off += NCHUNK * 8;                         // 128 KiB

    hipMemsetAsync(S, 0, 2046 * 2 * sizeof(float), stream);
    hipMemsetAsync(d_out, 0, sizeof(float), stream);

    // HODLR: w = diag*z + low-rank corrections
    kA_moments<<<NCHUNK / 4, 256, 0, stream>>>(z, M);
    kB_ssum<<<LEVELS, 1024, 0, stream>>>(M, V, S);
    kC_g<<<NCHUNK / 256, 256, 0, stream>>>(S, U, G);
    kW<<<N_NODES / 1024, 256, 0, stream>>>(diag, z, G, w);

    // Counting-sort binned SpMV + fused loss
    kHist<<<HBLOCKS, 256, 0, stream>>>(rows, blockOff);
    kScan1<<<NBUCK, 256, 0, stream>>>(blockOff, total);
    kScan2<<<1, NBUCK, 0, stream>>>(total, bbase);
    kBinScatter<<<HBLOCKS, 256, 0, stream>>>(rows, cols, Avals, w, blockOff, bbase, packed);
    kBucketAccum<<<NBUCK, 512, 0, stream>>>(packed, bbase, total, z, d_out ? (float*)d_out : nullptr);
}

// Round 3
// 346.627 us; speedup vs baseline: 1.6766x; 1.2661x over previous
//
#include <hip/hip_runtime.h>

#define N_NODES   4194304
#define LEVELS    10
#define COARSE    8192
#define NNZ_E     8388608
#define NCHUNK    16384   // N_NODES / 256
#define NBUCK     256     // row buckets
#define BROWS     16384   // rows per bucket (64 KiB LDS accumulator)
#define BSH       14      // row >> BSH = bucket
#define HBLOCKS   1024    // blocks in hist/scatter pass (8192 edges each)

static __device__ __forceinline__ unsigned short f2bf(float x) {
    unsigned u = __float_as_uint(x);
    return (unsigned short)((u + 0x7FFFu + ((u >> 16) & 1u)) >> 16);
}
static __device__ __forceinline__ float bf2f(unsigned short h) {
    return __uint_as_float((unsigned)h << 16);
}

// ---------------- Kernel A: per-256-chunk moments; block 0 zeros S and out
__global__ __launch_bounds__(256) void kA_moments(const float* __restrict__ z,
                                                  float2* __restrict__ M,
                                                  float* __restrict__ S,
                                                  float* __restrict__ out) {
    if (blockIdx.x == 0) {
        for (int i = threadIdx.x; i < 2046 * 2; i += 256) S[i] = 0.f;
        if (threadIdx.x == 0) out[0] = 0.f;
    }
    int lane = threadIdx.x & 63;
    int wave = threadIdx.x >> 6;
    int chunk = blockIdx.x * 4 + wave;
    int base = chunk * 256 + lane * 4;
    float4 zv = *(const float4*)(z + base);
    float a0 = 0.f, a1 = 0.f;
    const float* zp = (const float*)&zv;
#pragma unroll
    for (int j = 0; j < 4; ++j) {
        float p = ((float)(base + j) + 0.5f) * (1.0f / 512.0f) - 0.5f;
        p = fminf(fmaxf(p, 0.0f), (float)(COARSE - 1));
        float f = p - floorf(p);
        a0 += zp[j] * (1.0f - f);
        a1 += zp[j] * f;
    }
#pragma unroll
    for (int off = 32; off >= 1; off >>= 1) {
        a0 += __shfl_xor(a0, off, 64);
        a1 += __shfl_xor(a1, off, 64);
    }
    if (lane == 0) M[chunk] = make_float2(a0, a1);
}

// ---------------- Kernel B: block sums S[lvl][b][r] from moments
__global__ __launch_bounds__(1024) void kB_ssum(const float2* __restrict__ M,
                                                const float* __restrict__ V,
                                                float* __restrict__ S) {
    int lvl = blockIdx.x;
    int t = threadIdx.x;
    const float2* Vl = (const float2*)(V + lvl * COARSE * 2);
    float s0 = 0.f, s1 = 0.f;
    int c0 = t * 16;
#pragma unroll
    for (int cc = 0; cc < 16; ++cc) {
        int c = c0 + cc;
        float2 m = M[c];
        int k = (c > 0) ? ((c - 1) >> 1) : 0;
        int kp = min(k + 1, COARSE - 1);
        float2 vk = Vl[k], vkp = Vl[kp];
        s0 += vk.x * m.x + vkp.x * m.y;
        s1 += vk.y * m.x + vkp.y * m.y;
    }
    int gs = 1 << (9 - lvl);
    int gw = min(gs, 64);
    for (int sh = gw >> 1; sh >= 1; sh >>= 1) {
        s0 += __shfl_xor(s0, sh, 64);
        s1 += __shfl_xor(s1, sh, 64);
    }
    if ((t & (gw - 1)) == 0) {
        int b = t >> (9 - lvl);
        int soff = (2 << lvl) - 2;
        unsafeAtomicAdd(&S[(soff + b) * 2 + 0], s0);
        unsafeAtomicAdd(&S[(soff + b) * 2 + 1], s1);
    }
}

// ---------------- Kernel C: per-chunk coefficients G0,G1
__global__ __launch_bounds__(256) void kC_g(const float* __restrict__ S,
                                            const float* __restrict__ U,
                                            float2* __restrict__ G) {
    int c = blockIdx.x * 256 + threadIdx.x;
    int k = (c > 0) ? ((c - 1) >> 1) : 0;
    int kp = min(k + 1, COARSE - 1);
    float g0 = 0.f, g1 = 0.f;
#pragma unroll
    for (int lvl = 0; lvl < LEVELS; ++lvl) {
        int sib = (c >> (13 - lvl)) ^ 1;
        int soff = (2 << lvl) - 2;
        float2 s = ((const float2*)S)[soff + sib];
        const float2* Ul = (const float2*)(U + lvl * COARSE * 2);
        float2 uk = Ul[k], ukp = Ul[kp];
        g0 += uk.x * s.x + uk.y * s.y;
        g1 += ukp.x * s.x + ukp.y * s.y;
    }
    G[c] = make_float2(g0, g1);
}

// ---------------- Kernel W: w = diag*z + (1-f)*G0 + f*G1, stored as bf16
__global__ __launch_bounds__(256) void kW(const float* __restrict__ diag,
                                          const float* __restrict__ z,
                                          const float2* __restrict__ G,
                                          unsigned short* __restrict__ wb) {
    int tid = blockIdx.x * 256 + threadIdx.x;
    int base = tid * 4;
    float2 g = G[base >> 8];
    float4 d4 = *(const float4*)(diag + base);
    float4 z4 = *(const float4*)(z + base);
    const float* dp = (const float*)&d4;
    const float* zp = (const float*)&z4;
    ushort4 h4;
    unsigned short* hp = (unsigned short*)&h4;
#pragma unroll
    for (int j = 0; j < 4; ++j) {
        float p = ((float)(base + j) + 0.5f) * (1.0f / 512.0f) - 0.5f;
        p = fminf(fmaxf(p, 0.0f), (float)(COARSE - 1));
        float f = p - floorf(p);
        hp[j] = f2bf(dp[j] * zp[j] + (g.x + f * (g.y - g.x)));
    }
    *(ushort4*)(wb + base) = h4;
}

// ---------------- Kernel H: per-block bucket histogram
__global__ __launch_bounds__(256) void kHist(const int* __restrict__ rows,
                                             unsigned int* __restrict__ blockOff) {
    __shared__ unsigned int h[NBUCK];
    int blk = blockIdx.x, t = threadIdx.x;
    h[t] = 0u;
    __syncthreads();
    int base = blk * 8192;
#pragma unroll
    for (int it = 0; it < 8; ++it) {
        int e = base + it * 1024 + t * 4;
        int4 r = *(const int4*)(rows + e);
        atomicAdd(&h[r.x >> BSH], 1u);
        atomicAdd(&h[r.y >> BSH], 1u);
        atomicAdd(&h[r.z >> BSH], 1u);
        atomicAdd(&h[r.w >> BSH], 1u);
    }
    __syncthreads();
    blockOff[t * HBLOCKS + blk] = h[t];
}

// ---------------- Scan 1: per-bucket exclusive scan over 1024 block counts
__global__ __launch_bounds__(256) void kScan1(unsigned int* __restrict__ blockOff,
                                              unsigned int* __restrict__ total) {
    int b = blockIdx.x, t = threadIdx.x;
    unsigned int* p = blockOff + b * HBLOCKS;
    uint4 v = *(uint4*)(p + t * 4);
    unsigned int s = v.x + v.y + v.z + v.w;
    unsigned int incl = s;
#pragma unroll
    for (int off = 1; off < 64; off <<= 1) {
        unsigned int n = __shfl_up(incl, off, 64);
        if ((t & 63) >= off) incl += n;
    }
    __shared__ unsigned int wsum[4], wbase[4];
    if ((t & 63) == 63) wsum[t >> 6] = incl;
    __syncthreads();
    if (t == 0) {
        unsigned int acc = 0;
        for (int i = 0; i < 4; ++i) { wbase[i] = acc; acc += wsum[i]; }
        total[b] = acc;
    }
    __syncthreads();
    unsigned int excl = wbase[t >> 6] + incl - s;
    uint4 e;
    e.x = excl; e.y = excl + v.x; e.z = e.y + v.y; e.w = e.z + v.z;
    *(uint4*)(p + t * 4) = e;
}

// ---------------- Kernel S: bin edges; batched for MLP; bf16 gather
__global__ __launch_bounds__(256) void kBinScatter(const int* __restrict__ rows,
                                                   const int* __restrict__ cols,
                                                   const float* __restrict__ vals,
                                                   const unsigned short* __restrict__ wb,
                                                   const unsigned int* __restrict__ blockOff,
                                                   const unsigned int* __restrict__ total,
                                                   uint2* __restrict__ packed) {
    __shared__ unsigned int ctr[NBUCK];
    __shared__ unsigned int wsum[4], wbase[4];
    int blk = blockIdx.x, t = threadIdx.x;
    // in-block exclusive scan of total[0..255] -> bucket bases
    unsigned int tv = total[t];
    unsigned int incl = tv;
#pragma unroll
    for (int off = 1; off < 64; off <<= 1) {
        unsigned int n = __shfl_up(incl, off, 64);
        if ((t & 63) >= off) incl += n;
    }
    if ((t & 63) == 63) wsum[t >> 6] = incl;
    __syncthreads();
    if (t == 0) {
        unsigned int a = 0;
        for (int i = 0; i < 4; ++i) { wbase[i] = a; a += wsum[i]; }
    }
    __syncthreads();
    ctr[t] = (wbase[t >> 6] + incl - tv) + blockOff[t * HBLOCKS + blk];
    __syncthreads();

    int base = blk * 8192;
#pragma unroll
    for (int half = 0; half < 2; ++half) {
        int4 r[4], c[4];
        float4 v[4];
#pragma unroll
        for (int j = 0; j < 4; ++j) {
            int e = base + (half * 4 + j) * 1024 + t * 4;
            r[j] = *(const int4*)(rows + e);
            c[j] = *(const int4*)(cols + e);
            v[j] = *(const float4*)(vals + e);
        }
        unsigned short wv[16];
#pragma unroll
        for (int j = 0; j < 4; ++j) {
            const int* cp = (const int*)&c[j];
            wv[j * 4 + 0] = wb[cp[0]];
            wv[j * 4 + 1] = wb[cp[1]];
            wv[j * 4 + 2] = wb[cp[2]];
            wv[j * 4 + 3] = wb[cp[3]];
        }
#pragma unroll
        for (int j = 0; j < 4; ++j) {
            const int* rp = (const int*)&r[j];
            const float* vp = (const float*)&v[j];
#pragma unroll
            for (int k = 0; k < 4; ++k) {
                int row = rp[k];
                float p = vp[k] * bf2f(wv[j * 4 + k]);
                unsigned int pos = atomicAdd(&ctr[row >> BSH], 1u);
                packed[pos] = make_uint2((unsigned)(row & (BROWS - 1)), __float_as_uint(p));
            }
        }
    }
}

// ---------------- Kernel Acc: per-bucket LDS accumulation + fused loss
__global__ __launch_bounds__(1024) void kBucketAccum(const uint2* __restrict__ packed,
                                                     const unsigned int* __restrict__ total,
                                                     const float* __restrict__ z,
                                                     float* __restrict__ out) {
    __shared__ float acc[BROWS];          // 64 KiB
    __shared__ unsigned int sb, sn;
    __shared__ unsigned int wsum[4], wbase[4];
    __shared__ float red[16];
    int b = blockIdx.x, t = threadIdx.x;

    unsigned int tv = 0, incl = 0;
    if (t < 256) {
        tv = total[t];
        incl = tv;
#pragma unroll
        for (int off = 1; off < 64; off <<= 1) {
            unsigned int n = __shfl_up(incl, off, 64);
            if ((t & 63) >= off) incl += n;
        }
        if ((t & 63) == 63) wsum[t >> 6] = incl;
    }
    __syncthreads();
    if (t == 0) {
        unsigned int a = 0;
        for (int i = 0; i < 4; ++i) { wbase[i] = a; a += wsum[i]; }
    }
    __syncthreads();
    if (t < 256 && t == b) { sb = wbase[t >> 6] + incl - tv; sn = tv; }
    for (int i = t; i < BROWS / 4; i += 1024) ((float4*)acc)[i] = make_float4(0.f, 0.f, 0.f, 0.f);
    __syncthreads();

    unsigned int s0 = sb, n = sn;
    for (unsigned int i = t; i < n; i += 1024) {
        uint2 e = packed[s0 + i];
        atomicAdd(&acc[e.x], __uint_as_float(e.y));
    }
    __syncthreads();

    float part = 0.f;
    int gbase = b * BROWS;
    for (int i = t; i < BROWS; i += 1024) {
        float d = acc[i] - z[gbase + i];
        part += d * d;
    }
#pragma unroll
    for (int off = 32; off >= 1; off >>= 1) part += __shfl_xor(part, off, 64);
    if ((t & 63) == 0) red[t >> 6] = part;
    __syncthreads();
    if (t == 0) {
        float s = 0.f;
        for (int i = 0; i < 16; ++i) s += red[i];
        unsafeAtomicAdd(out, s * (1.0f / (float)N_NODES));
    }
}

extern "C" void kernel_launch(void* const* d_in, const int* in_sizes, int n_in,
                              void* d_out, int out_size, void* d_ws, size_t ws_size,
                              hipStream_t stream) {
    const float* diag  = (const float*)d_in[0];
    const float* U     = (const float*)d_in[1];
    const float* V     = (const float*)d_in[2];
    const float* Avals = (const float*)d_in[3];
    const float* z     = (const float*)d_in[4];
    const int*   Aidx  = (const int*)d_in[5];
    const int* rows = Aidx;
    const int* cols = Aidx + NNZ_E;

    char* ws = (char*)d_ws;
    size_t off = 0;
    unsigned short* wb = (unsigned short*)(ws + off); off += (size_t)N_NODES * 2;   // 8 MiB
    uint2* packed      = (uint2*)(ws + off);          off += (size_t)NNZ_E * 8;     // 64 MiB
    unsigned int* blockOff = (unsigned int*)(ws + off); off += (size_t)NBUCK * HBLOCKS * 4; // 1 MiB
    unsigned int* total    = (unsigned int*)(ws + off); off += NBUCK * 4;
    float2* M  = (float2*)(ws + off); off += NCHUNK * 8;
    float*  S  = (float*)(ws + off);  off += 2046 * 2 * 4;
    float2* G  = (float2*)(ws + off); off += NCHUNK * 8;

    // HODLR: w = diag*z + low-rank corrections (bf16 output)
    kA_moments<<<NCHUNK / 4, 256, 0, stream>>>(z, M, S, (float*)d_out);
    kB_ssum<<<LEVELS, 1024, 0, stream>>>(M, V, S);
    kC_g<<<NCHUNK / 256, 256, 0, stream>>>(S, U, G);
    kW<<<N_NODES / 1024, 256, 0, stream>>>(diag, z, G, wb);

    // Counting-sort binned SpMV + fused loss
    kHist<<<HBLOCKS, 256, 0, stream>>>(rows, blockOff);
    kScan1<<<NBUCK, 256, 0, stream>>>(blockOff, total);
    kBinScatter<<<HBLOCKS, 256, 0, stream>>>(rows, cols, Avals, wb, blockOff, total, packed);
    kBucketAccum<<<NBUCK, 1024, 0, stream>>>(packed, total, z, (float*)d_out);
}

// Round 4
// 341.618 us; speedup vs baseline: 1.7012x; 1.0147x over previous
//
#include <hip/hip_runtime.h>

#define N_NODES   4194304
#define LEVELS    10
#define COARSE    8192
#define NNZ_E     8388608
#define NCHUNK    16384   // N_NODES / 256
#define NBUCK     256     // row buckets
#define BROWS     16384   // rows per bucket (64 KiB LDS accumulator)
#define BSH       14      // row >> BSH = bucket
#define HBLOCKS   2048    // blocks in hist/scatter pass
#define EPB       4096    // edges per hist/scatter block

typedef int          v4i __attribute__((ext_vector_type(4)));
typedef float        v4f __attribute__((ext_vector_type(4)));
typedef unsigned int v4u __attribute__((ext_vector_type(4)));

static __device__ __forceinline__ unsigned short f2bf(float x) {
    unsigned u = __float_as_uint(x);
    return (unsigned short)((u + 0x7FFFu + ((u >> 16) & 1u)) >> 16);
}
static __device__ __forceinline__ float bf2f(unsigned short h) {
    return __uint_as_float((unsigned)h << 16);
}
// pack: 14-bit local row | 18-bit float (1s+8e+9m, round-to-nearest)
static __device__ __forceinline__ unsigned pack18(int lrow, float p) {
    unsigned u = __float_as_uint(p);
    return ((unsigned)lrow << 18) | (((u + 0x2000u) >> 14) & 0x3FFFFu);
}

// ---------------- Kernel A: per-256-chunk moments; block 0 zeros S and out
__global__ __launch_bounds__(256) void kA_moments(const float* __restrict__ z,
                                                  float2* __restrict__ M,
                                                  float* __restrict__ S,
                                                  float* __restrict__ out) {
    if (blockIdx.x == 0) {
        for (int i = threadIdx.x; i < 2046 * 2; i += 256) S[i] = 0.f;
        if (threadIdx.x == 0) out[0] = 0.f;
    }
    int lane = threadIdx.x & 63;
    int wave = threadIdx.x >> 6;
    int chunk = blockIdx.x * 4 + wave;
    int base = chunk * 256 + lane * 4;
    float4 zv = *(const float4*)(z + base);
    float a0 = 0.f, a1 = 0.f;
    const float* zp = (const float*)&zv;
#pragma unroll
    for (int j = 0; j < 4; ++j) {
        float p = ((float)(base + j) + 0.5f) * (1.0f / 512.0f) - 0.5f;
        p = fminf(fmaxf(p, 0.0f), (float)(COARSE - 1));
        float f = p - floorf(p);
        a0 += zp[j] * (1.0f - f);
        a1 += zp[j] * f;
    }
#pragma unroll
    for (int off = 32; off >= 1; off >>= 1) {
        a0 += __shfl_xor(a0, off, 64);
        a1 += __shfl_xor(a1, off, 64);
    }
    if (lane == 0) M[chunk] = make_float2(a0, a1);
}

// ---------------- Kernel B: block sums S[lvl][b][r]; 8 slices per level
__global__ __launch_bounds__(1024) void kB_ssum(const float2* __restrict__ M,
                                                const float* __restrict__ V,
                                                float* __restrict__ S) {
    int lvl = blockIdx.x >> 3;
    int slice = blockIdx.x & 7;
    int t = threadIdx.x;
    const float2* Vl = (const float2*)(V + lvl * COARSE * 2);
    float s0 = 0.f, s1 = 0.f;
    int c0 = slice * 2048 + t * 2;
#pragma unroll
    for (int cc = 0; cc < 2; ++cc) {
        int c = c0 + cc;
        float2 m = M[c];
        int k = (c > 0) ? ((c - 1) >> 1) : 0;
        int kp = min(k + 1, COARSE - 1);
        float2 vk = Vl[k], vkp = Vl[kp];
        s0 += vk.x * m.x + vkp.x * m.y;
        s1 += vk.y * m.x + vkp.y * m.y;
    }
    int tpg_sh = 12 - lvl;                 // log2(threads per group), >= 3
    int gw = min(1 << tpg_sh, 64);
    for (int sh = gw >> 1; sh >= 1; sh >>= 1) {
        s0 += __shfl_xor(s0, sh, 64);
        s1 += __shfl_xor(s1, sh, 64);
    }
    if ((t & (gw - 1)) == 0) {
        int b = c0 >> (13 - lvl);          // global block index at this level
        int soff = (2 << lvl) - 2;
        unsafeAtomicAdd(&S[(soff + b) * 2 + 0], s0);
        unsafeAtomicAdd(&S[(soff + b) * 2 + 1], s1);
    }
}

// ---------------- Kernel C: per-chunk coefficients G0,G1
__global__ __launch_bounds__(256) void kC_g(const float* __restrict__ S,
                                            const float* __restrict__ U,
                                            float2* __restrict__ G) {
    int c = blockIdx.x * 256 + threadIdx.x;
    int k = (c > 0) ? ((c - 1) >> 1) : 0;
    int kp = min(k + 1, COARSE - 1);
    float g0 = 0.f, g1 = 0.f;
#pragma unroll
    for (int lvl = 0; lvl < LEVELS; ++lvl) {
        int sib = (c >> (13 - lvl)) ^ 1;
        int soff = (2 << lvl) - 2;
        float2 s = ((const float2*)S)[soff + sib];
        const float2* Ul = (const float2*)(U + lvl * COARSE * 2);
        float2 uk = Ul[k], ukp = Ul[kp];
        g0 += uk.x * s.x + uk.y * s.y;
        g1 += ukp.x * s.x + ukp.y * s.y;
    }
    G[c] = make_float2(g0, g1);
}

// ---------------- Kernel W: w = diag*z + (1-f)*G0 + f*G1, stored as bf16
__global__ __launch_bounds__(256) void kW(const float* __restrict__ diag,
                                          const float* __restrict__ z,
                                          const float2* __restrict__ G,
                                          unsigned short* __restrict__ wb) {
    int tid = blockIdx.x * 256 + threadIdx.x;
    int base = tid * 4;
    float2 g = G[base >> 8];
    v4f d4 = __builtin_nontemporal_load((const v4f*)(diag + base));
    v4f z4 = __builtin_nontemporal_load((const v4f*)(z + base));
    const float* dp = (const float*)&d4;
    const float* zp = (const float*)&z4;
    ushort4 h4;
    unsigned short* hp = (unsigned short*)&h4;
#pragma unroll
    for (int j = 0; j < 4; ++j) {
        float p = ((float)(base + j) + 0.5f) * (1.0f / 512.0f) - 0.5f;
        p = fminf(fmaxf(p, 0.0f), (float)(COARSE - 1));
        float f = p - floorf(p);
        hp[j] = f2bf(dp[j] * zp[j] + (g.x + f * (g.y - g.x)));
    }
    *(ushort4*)(wb + base) = h4;
}

// ---------------- Kernel H: per-block bucket histogram (4096 edges/block)
__global__ __launch_bounds__(256) void kHist(const int* __restrict__ rows,
                                             unsigned int* __restrict__ blockOff) {
    __shared__ unsigned int h[NBUCK];
    int blk = blockIdx.x, t = threadIdx.x;
    h[t] = 0u;
    __syncthreads();
    int base = blk * EPB;
#pragma unroll
    for (int it = 0; it < 4; ++it) {
        int e = base + it * 1024 + t * 4;
        v4i r = __builtin_nontemporal_load((const v4i*)(rows + e));
        atomicAdd(&h[r.x >> BSH], 1u);
        atomicAdd(&h[r.y >> BSH], 1u);
        atomicAdd(&h[r.z >> BSH], 1u);
        atomicAdd(&h[r.w >> BSH], 1u);
    }
    __syncthreads();
    blockOff[t * HBLOCKS + blk] = h[t];
}

// ---------------- Scan 1: per-bucket exclusive scan over 2048 block counts
__global__ __launch_bounds__(256) void kScan1(unsigned int* __restrict__ blockOff,
                                              unsigned int* __restrict__ total) {
    int b = blockIdx.x, t = threadIdx.x;
    unsigned int* p = blockOff + b * HBLOCKS;
    v4u a = *(const v4u*)(p + t * 8);
    v4u c = *(const v4u*)(p + t * 8 + 4);
    unsigned int s = a.x + a.y + a.z + a.w + c.x + c.y + c.z + c.w;
    unsigned int incl = s;
#pragma unroll
    for (int off = 1; off < 64; off <<= 1) {
        unsigned int n = __shfl_up(incl, off, 64);
        if ((t & 63) >= off) incl += n;
    }
    __shared__ unsigned int wsum[4], wbase[4];
    if ((t & 63) == 63) wsum[t >> 6] = incl;
    __syncthreads();
    if (t == 0) {
        unsigned int acc = 0;
        for (int i = 0; i < 4; ++i) { wbase[i] = acc; acc += wsum[i]; }
        total[b] = acc;
    }
    __syncthreads();
    unsigned int excl = wbase[t >> 6] + incl - s;
    v4u e0, e1;
    e0.x = excl;        e0.y = e0.x + a.x; e0.z = e0.y + a.y; e0.w = e0.z + a.z;
    e1.x = e0.w + a.w;  e1.y = e1.x + c.x; e1.z = e1.y + c.y; e1.w = e1.z + c.z;
    *(v4u*)(p + t * 8) = e0;
    *(v4u*)(p + t * 8 + 4) = e1;
}

// ---------------- Kernel S: bin edges, 16/thread fully batched, 4B packed
__global__ __launch_bounds__(256) void kBinScatter(const int* __restrict__ rows,
                                                   const int* __restrict__ cols,
                                                   const float* __restrict__ vals,
                                                   const unsigned short* __restrict__ wb,
                                                   const unsigned int* __restrict__ blockOff,
                                                   const unsigned int* __restrict__ total,
                                                   unsigned int* __restrict__ packed) {
    __shared__ unsigned int ctr[NBUCK];
    __shared__ unsigned int wsum[4], wbase[4];
    int blk = blockIdx.x, t = threadIdx.x;
    unsigned int tv = total[t];
    unsigned int incl = tv;
#pragma unroll
    for (int off = 1; off < 64; off <<= 1) {
        unsigned int n = __shfl_up(incl, off, 64);
        if ((t & 63) >= off) incl += n;
    }
    if ((t & 63) == 63) wsum[t >> 6] = incl;
    __syncthreads();
    if (t == 0) {
        unsigned int a = 0;
        for (int i = 0; i < 4; ++i) { wbase[i] = a; a += wsum[i]; }
    }
    __syncthreads();
    ctr[t] = (wbase[t >> 6] + incl - tv) + blockOff[t * HBLOCKS + blk];
    __syncthreads();

    int base = blk * EPB;
    v4i r[4], c[4];
    v4f v[4];
#pragma unroll
    for (int j = 0; j < 4; ++j) {
        int e = base + j * 1024 + t * 4;
        r[j] = __builtin_nontemporal_load((const v4i*)(rows + e));
        c[j] = __builtin_nontemporal_load((const v4i*)(cols + e));
        v[j] = __builtin_nontemporal_load((const v4f*)(vals + e));
    }
    unsigned short wv[16];
#pragma unroll
    for (int j = 0; j < 4; ++j) {
        const int* cp = (const int*)&c[j];
        wv[j * 4 + 0] = wb[cp[0]];
        wv[j * 4 + 1] = wb[cp[1]];
        wv[j * 4 + 2] = wb[cp[2]];
        wv[j * 4 + 3] = wb[cp[3]];
    }
#pragma unroll
    for (int j = 0; j < 4; ++j) {
        const int* rp = (const int*)&r[j];
        const float* vp = (const float*)&v[j];
#pragma unroll
        for (int k = 0; k < 4; ++k) {
            int row = rp[k];
            float p = vp[k] * bf2f(wv[j * 4 + k]);
            unsigned int pos = atomicAdd(&ctr[row >> BSH], 1u);
            packed[pos] = pack18(row & (BROWS - 1), p);
        }
    }
}

// ---------------- Kernel Acc: per-bucket LDS accumulation + fused loss
__global__ __launch_bounds__(1024) void kBucketAccum(const unsigned int* __restrict__ packed,
                                                     const unsigned int* __restrict__ total,
                                                     const float* __restrict__ z,
                                                     float* __restrict__ out) {
    __shared__ float acc[BROWS];          // 64 KiB
    __shared__ unsigned int sb, sn;
    __shared__ unsigned int wsum[4], wbase[4];
    __shared__ float red[16];
    int b = blockIdx.x, t = threadIdx.x;

    unsigned int tv = 0, incl = 0;
    if (t < 256) {
        tv = total[t];
        incl = tv;
#pragma unroll
        for (int off = 1; off < 64; off <<= 1) {
            unsigned int n = __shfl_up(incl, off, 64);
            if ((t & 63) >= off) incl += n;
        }
        if ((t & 63) == 63) wsum[t >> 6] = incl;
    }
    __syncthreads();
    if (t == 0) {
        unsigned int a = 0;
        for (int i = 0; i < 4; ++i) { wbase[i] = a; a += wsum[i]; }
    }
    __syncthreads();
    if (t < 256 && t == b) { sb = wbase[t >> 6] + incl - tv; sn = tv; }
    for (int i = t; i < BROWS / 4; i += 1024) ((float4*)acc)[i] = make_float4(0.f, 0.f, 0.f, 0.f);
    __syncthreads();

    unsigned int s0 = sb, n = sn;
    for (unsigned int i = t; i < n; i += 1024) {
        unsigned int e = __builtin_nontemporal_load(packed + s0 + i);
        atomicAdd(&acc[e >> 18], __uint_as_float((e & 0x3FFFFu) << 14));
    }
    __syncthreads();

    float part = 0.f;
    int gbase = b * BROWS;
    for (int i = t; i < BROWS; i += 1024) {
        float d = acc[i] - z[gbase + i];
        part += d * d;
    }
#pragma unroll
    for (int off = 32; off >= 1; off >>= 1) part += __shfl_xor(part, off, 64);
    if ((t & 63) == 0) red[t >> 6] = part;
    __syncthreads();
    if (t == 0) {
        float s = 0.f;
        for (int i = 0; i < 16; ++i) s += red[i];
        unsafeAtomicAdd(out, s * (1.0f / (float)N_NODES));
    }
}

extern "C" void kernel_launch(void* const* d_in, const int* in_sizes, int n_in,
                              void* d_out, int out_size, void* d_ws, size_t ws_size,
                              hipStream_t stream) {
    const float* diag  = (const float*)d_in[0];
    const float* U     = (const float*)d_in[1];
    const float* V     = (const float*)d_in[2];
    const float* Avals = (const float*)d_in[3];
    const float* z     = (const float*)d_in[4];
    const int*   Aidx  = (const int*)d_in[5];
    const int* rows = Aidx;
    const int* cols = Aidx + NNZ_E;

    char* ws = (char*)d_ws;
    size_t off = 0;
    unsigned short* wb = (unsigned short*)(ws + off); off += (size_t)N_NODES * 2;   // 8 MiB
    unsigned int* packed = (unsigned int*)(ws + off); off += (size_t)NNZ_E * 4;     // 32 MiB
    unsigned int* blockOff = (unsigned int*)(ws + off); off += (size_t)NBUCK * HBLOCKS * 4; // 2 MiB
    unsigned int* total    = (unsigned int*)(ws + off); off += NBUCK * 4;
    float2* M  = (float2*)(ws + off); off += NCHUNK * 8;
    float*  S  = (float*)(ws + off);  off += 2046 * 2 * 4;
    float2* G  = (float2*)(ws + off); off += NCHUNK * 8;

    // HODLR: w = diag*z + low-rank corrections (bf16 output)
    kA_moments<<<NCHUNK / 4, 256, 0, stream>>>(z, M, S, (float*)d_out);
    kB_ssum<<<LEVELS * 8, 1024, 0, stream>>>(M, V, S);
    kC_g<<<NCHUNK / 256, 256, 0, stream>>>(S, U, G);
    kW<<<N_NODES / 1024, 256, 0, stream>>>(diag, z, G, wb);

    // Counting-sort binned SpMV + fused loss
    kHist<<<HBLOCKS, 256, 0, stream>>>(rows, blockOff);
    kScan1<<<NBUCK, 256, 0, stream>>>(blockOff, total);
    kBinScatter<<<HBLOCKS, 256, 0, stream>>>(rows, cols, Avals, wb, blockOff, total, packed);
    kBucketAccum<<<NBUCK, 1024, 0, stream>>>(packed, total, z, (float*)d_out);
}